// Round 1
// baseline (379.689 us; speedup 1.0000x reference)
//
#include <hip/hip_runtime.h>

#define HW 36864      // 192*192
#define IMGS 128      // B*C

static __device__ __forceinline__ int imax(int a, int b) { return a > b ? a : b; }
static __device__ __forceinline__ int imin(int a, int b) { return a < b ? a : b; }

__device__ __constant__ float LIFT_C[6] = {
  -0.5f, 0.25f,                                            // bior53
  -1.586134342f, -0.05298011854f, 0.8829110762f, 0.4435068522f  // bior97
};

// raw (unnormalized) FIR lowpass filters concatenated: db4(8) db6(12) sym6(12) coif5(30)
__device__ constexpr float FIRC[62] = {
  -0.0105974017850021f, 0.0328830116668852f, 0.0308413818355607f, -0.1870348117188811f,
  -0.0279837694169839f, 0.6308807679295904f, 0.7148465705529155f, 0.2303778133088964f,
  0.00107730108499558f, -0.00477725751101065f, -0.0005538422009938f, 0.03158203931748603f,
  0.02752286553030533f, -0.0975016055873225f, -0.12976686756709563f, 0.22626469396544f,
  0.3152503517092432f, -0.7511339080210959f, 0.4946238903984534f, 0.1115407433501095f,
  -0.007800708325034148f, 0.001767711864242804f, 0.04472490177066578f, -0.02106029251230056f,
  -0.0726375227866f, 0.3379294217282401f, 0.787641141030194f, 0.4910559419267466f,
  -0.048311742585632f, -0.1179901111484105f, 0.00349071208421747f, 0.01540410932702737f,
  -3.459977283621256e-05f, -7.098330313814114e-05f, 0.0004662169601128863f, 0.001117518770890601f,
  -0.002574517688750223f, -0.00900797613666158f, 0.015880544863615904f, 0.03455502757306163f,
  -0.08230192710688598f, -0.07179982161931202f, 0.42848347637761874f, 0.7937772226256206f,
  0.4051769024096169f, -0.06112339000267287f, -0.06577191128185562f, 0.023452696141836267f,
  0.007782596427325418f, -0.003793512864491014f, -0.0002606761356811993f, 0.000107502882505652f,
  1.10319778524429e-05f, -5.520763127949e-06f, -1.0682196848076e-06f, 5.236425333584e-07f,
  1.125098976034e-07f, -5.417490769329e-08f, -8.8631e-09f, 4.2921e-09f, 6.7e-10f, -3.2e-10f,
};

// ---------------- gate: 1x1 conv -> relu -> 1x1 conv -> softmax -> renorm ----------------
__global__ __launch_bounds__(256) void k_gate(
    const float* __restrict__ x, const float* __restrict__ w1, const float* __restrict__ b1,
    const float* __restrict__ w2, const float* __restrict__ b2, float* __restrict__ gate)
{
  __shared__ float w1s[256], b1s[8], w2s[48], b2s[6];
  int tid = threadIdx.x;
  w1s[tid] = w1[tid];
  if (tid < 8)  b1s[tid] = b1[tid];
  if (tid < 48) w2s[tid] = w2[tid];
  if (tid < 6)  b2s[tid] = b2[tid];
  __syncthreads();
  int px = blockIdx.x * 256 + tid;        // exactly 4*HW threads
  int b = px / HW, p = px - b * HW;
  const float* xb = x + (size_t)b * 32 * HW + p;
  float xv[32];
#pragma unroll
  for (int c = 0; c < 32; ++c) xv[c] = xb[(size_t)c * HW];
  float hb[8];
#pragma unroll
  for (int j = 0; j < 8; ++j) {
    float s = b1s[j];
#pragma unroll
    for (int c = 0; c < 32; ++c) s += w1s[j * 32 + c] * xv[c];
    hb[j] = fmaxf(s, 0.f);
  }
  float e[6], mx = -1e30f;
#pragma unroll
  for (int k = 0; k < 6; ++k) {
    float s = b2s[k];
#pragma unroll
    for (int j = 0; j < 8; ++j) s += w2s[k * 8 + j] * hb[j];
    e[k] = s; mx = fmaxf(mx, s);
  }
  float se = 0.f;
#pragma unroll
  for (int k = 0; k < 6; ++k) { e[k] = expf(e[k] - mx); se += e[k]; }
  float inv = 1.f / se, s2 = 0.f;
#pragma unroll
  for (int k = 0; k < 6; ++k) { e[k] *= inv; s2 += e[k]; }
  float inv2 = 1.f / (s2 + 1e-12f);
  float* gp = gate + (size_t)b * 6 * HW + p;
#pragma unroll
  for (int k = 0; k < 6; ++k) gp[(size_t)k * HW] = e[k] * inv2;
}

// ---------------- lifting W pass: one row per block ----------------
__global__ __launch_bounds__(192) void k_wlift(
    const float* __restrict__ x, float* __restrict__ aw, float* __restrict__ dw,
    const float* __restrict__ sAp, const float* __restrict__ sDp, int stepbase, int nsteps)
{
  __shared__ float xs[192], ev[96], od[96];
  int tid = threadIdx.x;
  int row = blockIdx.x, img = blockIdx.y;
  xs[tid] = x[((size_t)img * 192 + row) * 192 + tid];
  __syncthreads();
  if (tid < 96) { ev[tid] = xs[2 * tid]; od[tid] = xs[2 * tid + 1]; }
  __syncthreads();
  int jm = (tid == 0) ? 1 : tid - 1;
  int jp = (tid == 95) ? 94 : tid + 1;
  for (int s = 0; s < nsteps; ++s) {
    float cf = LIFT_C[stepbase + s];
    if (tid < 96) {
      if ((s & 1) == 0) od[tid] += cf * 0.5f * (ev[jm] + ev[jp]);
      else              ev[tid] += cf * 0.5f * (od[jm] + od[jp]);
    }
    __syncthreads();
  }
  if (tid < 96) {
    size_t o = ((size_t)img * 192 + row) * 96 + tid;
    aw[o] = sAp[0] * ev[tid];
    dw[o] = sDp[0] * od[tid];
  }
}

// ---------------- lifting H pass: 8 columns per block ----------------
__global__ __launch_bounds__(768) void k_hlift(
    const float* __restrict__ awdw, float* __restrict__ halfc,
    const float* __restrict__ sAp, const float* __restrict__ sDp,
    const float* __restrict__ hfp, int stepbase, int nsteps)
{
  __shared__ float ev[96 * 8], od[96 * 8];
  int tid = threadIdx.x;
  int c = tid & 7, j = tid >> 3;               // j: 0..95 half-row
  int cg = blockIdx.x, img = blockIdx.y, sel = blockIdx.z;
  int col = cg * 8 + c;
  const float* P = awdw + ((size_t)sel * IMGS + img) * (192 * 96);
  ev[j * 8 + c] = P[(2 * j) * 96 + col];
  od[j * 8 + c] = P[(2 * j + 1) * 96 + col];
  __syncthreads();
  int jm = (j == 0) ? 1 : j - 1;
  int jp = (j == 95) ? 94 : j + 1;
  for (int s = 0; s < nsteps; ++s) {
    float cf = LIFT_C[stepbase + s];
    if ((s & 1) == 0) od[j * 8 + c] += cf * 0.5f * (ev[jm * 8 + c] + ev[jp * 8 + c]);
    else              ev[j * 8 + c] += cf * 0.5f * (od[jm * 8 + c] + od[jp * 8 + c]);
    __syncthreads();
  }
  float hf = hfp[0];
  float fA = sAp[0] * (sel ? hf : 1.f);   // LL no hf; HL has hf
  float fD = sDp[0] * hf;                 // LH/HH have hf
  size_t o0 = ((size_t)(sel * 2 + 0) * IMGS + img) * 9216 + (size_t)j * 96 + col;
  size_t o1 = ((size_t)(sel * 2 + 1) * IMGS + img) * 9216 + (size_t)j * 96 + col;
  halfc[o0] = fA * ev[j * 8 + c];
  halfc[o1] = fD * od[j * 8 + c];
}

// ---------------- fused FIR candidate (one candidate, 32x32 tile) ----------------
template<int L, int PA, int OFF>
__device__ __forceinline__ void fir_cand(
    const float* xt, float* lbs, float* hbs,
    int tid, int h0, int w0, float hf, const float (&gw4)[4], float (&acc)[4][4])
{
  float ss = 0.f;
#pragma unroll
  for (int j = 0; j < L; ++j) ss += FIRC[OFF + j] * FIRC[OFF + j];
  const float invn = 1.f / (sqrtf(ss) + 1e-12f);
  const float SC = 190.f / 192.f;

  // ---- W pass: rows [h0-16,h0+47], blended output cols (resize fused) ----
  {
    const int row = tid >> 2, g = tid & 3;
    const int wf = w0 + g * 8;
    const float f0 = ((float)wf + 0.5f) * SC - 0.5f;
    const int qs = (int)floorf(f0);
    const int xb = row * 65 + (qs - w0 + 16 - PA);
    float win[L + 8];
#pragma unroll
    for (int m = 0; m < L + 8; ++m) win[m] = xt[xb + m];
    float Lp[9], Hp[9];
#pragma unroll
    for (int p = 0; p < 9; ++p) {
      float a = 0.f, d = 0.f;
#pragma unroll
      for (int j = 0; j < L; ++j) {
        const float v = win[p + j];
        a += FIRC[OFF + j] * v;
        d += (((j & 1) ? -1.f : 1.f) * FIRC[OFF + L - 1 - j]) * v;
      }
      Lp[p] = a; Hp[p] = d;
    }
#pragma unroll
    for (int k = 0; k < 8; ++k) {
      const int w = wf + k;
      const float fw = ((float)w + 0.5f) * SC - 0.5f;
      const int q0 = (int)floorf(fw);
      const float t = fw - (float)q0;
      const int i0 = imax(q0, 0) - qs;
      const int i1 = imin(q0 + 1, 189) - qs;
      const int e = i0 - k;
      const int km = (k > 0) ? (k - 1) : 0;
      const int kp = (k + 1 < 9) ? (k + 1) : 8;
      const int kq = (k + 2 < 9) ? (k + 2) : 8;
      float v0l = (e < 0) ? Lp[km] : ((e > 0) ? Lp[kp] : Lp[k]);
      float v1l = (i1 == i0) ? v0l : ((e < 0) ? Lp[k] : ((e > 0) ? Lp[kq] : Lp[kp]));
      float v0h = (e < 0) ? Hp[km] : ((e > 0) ? Hp[kp] : Hp[k]);
      float v1h = (i1 == i0) ? v0h : ((e < 0) ? Hp[k] : ((e > 0) ? Hp[kq] : Hp[kp]));
      lbs[row * 33 + g * 8 + k] = invn * ((1.f - t) * v0l + t * v1l);
      hbs[row * 33 + g * 8 + k] = invn * ((1.f - t) * v0h + t * v1h);
    }
  }
  __syncthreads();
  // ---- H pass: 5 conv positions per thread, row-blend into gated accumulators ----
  {
    const int c = tid & 31, g2 = tid >> 5;
    const int hfirst = h0 + g2 * 4;
    const float f0 = ((float)hfirst + 0.5f) * SC - 0.5f;
    const int rs = (int)floorf(f0);
    const int rb = rs - h0 + 16 - PA;
    float LLp[5], LHp[5], HLp[5], HHp[5];
    {
      float win[L + 4];
#pragma unroll
      for (int m = 0; m < L + 4; ++m) win[m] = lbs[(rb + m) * 33 + c];
#pragma unroll
      for (int p = 0; p < 5; ++p) {
        float a = 0.f, d = 0.f;
#pragma unroll
        for (int j = 0; j < L; ++j) {
          const float v = win[p + j];
          a += FIRC[OFF + j] * v;
          d += (((j & 1) ? -1.f : 1.f) * FIRC[OFF + L - 1 - j]) * v;
        }
        LLp[p] = a; LHp[p] = d;
      }
    }
    {
      float win[L + 4];
#pragma unroll
      for (int m = 0; m < L + 4; ++m) win[m] = hbs[(rb + m) * 33 + c];
#pragma unroll
      for (int p = 0; p < 5; ++p) {
        float a = 0.f, d = 0.f;
#pragma unroll
        for (int j = 0; j < L; ++j) {
          const float v = win[p + j];
          a += FIRC[OFF + j] * v;
          d += (((j & 1) ? -1.f : 1.f) * FIRC[OFF + L - 1 - j]) * v;
        }
        HLp[p] = a; HHp[p] = d;
      }
    }
#pragma unroll
    for (int k = 0; k < 4; ++k) {
      const int h = hfirst + k;
      const float fh = ((float)h + 0.5f) * SC - 0.5f;
      const int r0 = (int)floorf(fh);
      const float t = fh - (float)r0;
      const int i0 = imax(r0, 0) - rs;
      const int i1 = imin(r0 + 1, 189) - rs;
      const int e = i0 - k;
      const int km = (k > 0) ? (k - 1) : 0;
      const int kp = (k + 1 < 5) ? (k + 1) : 4;
      const int kq = (k + 2 < 5) ? (k + 2) : 4;
      const float u = 1.f - t;
      float vs[4];
      {
        float v0 = (e < 0) ? LLp[km] : ((e > 0) ? LLp[kp] : LLp[k]);
        float v1 = (i1 == i0) ? v0 : ((e < 0) ? LLp[k] : ((e > 0) ? LLp[kq] : LLp[kp]));
        vs[0] = invn * (u * v0 + t * v1);
      }
      {
        float v0 = (e < 0) ? LHp[km] : ((e > 0) ? LHp[kp] : LHp[k]);
        float v1 = (i1 == i0) ? v0 : ((e < 0) ? LHp[k] : ((e > 0) ? LHp[kq] : LHp[kp]));
        vs[1] = invn * (u * v0 + t * v1) * hf;
      }
      {
        float v0 = (e < 0) ? HLp[km] : ((e > 0) ? HLp[kp] : HLp[k]);
        float v1 = (i1 == i0) ? v0 : ((e < 0) ? HLp[k] : ((e > 0) ? HLp[kq] : HLp[kp]));
        vs[2] = invn * (u * v0 + t * v1) * hf;
      }
      {
        float v0 = (e < 0) ? HHp[km] : ((e > 0) ? HHp[kp] : HHp[k]);
        float v1 = (i1 == i0) ? v0 : ((e < 0) ? HHp[k] : ((e > 0) ? HHp[kq] : HHp[kp]));
        vs[3] = invn * (u * v0 + t * v1) * hf;
      }
      const float gv = gw4[k];
#pragma unroll
      for (int s = 0; s < 4; ++s) acc[k][s] += gv * vs[s];
    }
  }
  __syncthreads();
}

// ---------------- fused per-tile kernel: 4 FIR cands + lifting gather + gate ----------------
__global__ __launch_bounds__(256) void k3_fused(
    const float* __restrict__ x, const float* __restrict__ gate,
    const float* __restrict__ halfp, const float* __restrict__ hfp, float* __restrict__ sf)
{
  __shared__ float xt[64 * 65];
  __shared__ float wb[2 * 64 * 33];
  float* lbs = wb;
  float* hbs = wb + 64 * 33;
  int tid = threadIdx.x;
  int tile = blockIdx.x;
  int ty = tile / 6, tx = tile - ty * 6;
  int img = blockIdx.y;
  int b = img >> 5;
  int h0 = ty * 32, w0 = tx * 32;
  float hfv = hfp[0];

  const float* xi = x + (size_t)img * HW;
  for (int v = tid; v < 64 * 64; v += 256) {
    int l = v >> 6, m = v & 63;
    int ar = h0 - 16 + l; ar = ar < 0 ? -ar : (ar > 191 ? 382 - ar : ar);
    int ac = w0 - 16 + m; ac = ac < 0 ? -ac : (ac > 191 ? 382 - ac : ac);
    xt[l * 65 + m] = xi[ar * 192 + ac];
  }

  // pixel-role mapping: col c, 4 rows (g2*4+k)
  const int c = tid & 31, g2 = tid >> 5;
  const int wpx = w0 + c;
  float gw[6][4];
#pragma unroll
  for (int kk = 0; kk < 6; ++kk) {
    const float* gp = gate + (size_t)(b * 6 + kk) * HW + wpx;
#pragma unroll
    for (int k = 0; k < 4; ++k) gw[kk][k] = gp[(h0 + g2 * 4 + k) * 192];
  }
  float acc[4][4];
#pragma unroll
  for (int k = 0; k < 4; ++k)
#pragma unroll
    for (int s = 0; s < 4; ++s) acc[k][s] = 0.f;
  __syncthreads();

  fir_cand<8, 2, 0>(xt, lbs, hbs, tid, h0, w0, hfv, gw[0], acc);
  fir_cand<12, 4, 8>(xt, lbs, hbs, tid, h0, w0, hfv, gw[1], acc);
  fir_cand<12, 4, 20>(xt, lbs, hbs, tid, h0, w0, hfv, gw[2], acc);
  fir_cand<30, 13, 32>(xt, lbs, hbs, tid, h0, w0, hfv, gw[3], acc);

  // ---- lifting gather: stage 18x18 half-res windows of 8 planes as [pos][4] ----
  float* ls4 = wb;   // reuse (2592 <= 4224 floats)
  const int hu0 = (h0 >> 1) - 1, wv0 = (w0 >> 1) - 1;
  for (int v = tid; v < 2592; v += 256) {
    int lv = v % 18; int r1 = v / 18;
    int lu = r1 % 18; int ps = r1 / 18;      // ps = lc*4+s
    int lc = ps >> 2;
    int gu = imin(imax(hu0 + lu, 0), 95);
    int gv = imin(imax(wv0 + lv, 0), 95);
    ls4[(lc * 324 + lu * 18 + lv) * 4 + (ps & 3)] =
        halfp[((size_t)ps * IMGS + img) * 9216 + (size_t)gu * 96 + gv];
  }
  __syncthreads();

  const int v0c = (wpx >> 1) + (wpx & 1) - 1;
  const float tv = (wpx & 1) ? 0.25f : 0.75f;
  const int lv0 = imax(v0c, 0) - wv0;
  const int lv1 = imin(v0c + 1, 95) - wv0;
#pragma unroll
  for (int k = 0; k < 4; ++k) {
    const int h = h0 + g2 * 4 + k;
    const int u0 = (h >> 1) + (h & 1) - 1;
    const float tu = (h & 1) ? 0.25f : 0.75f;
    const int lu0 = imax(u0, 0) - hu0;
    const int lu1 = imin(u0 + 1, 95) - hu0;
    const float w00 = (1.f - tu) * (1.f - tv), w01 = (1.f - tu) * tv;
    const float w10 = tu * (1.f - tv), w11 = tu * tv;
#pragma unroll
    for (int lc = 0; lc < 2; ++lc) {
      const int b00 = (lc * 324 + lu0 * 18 + lv0) * 4;
      const int b01 = (lc * 324 + lu0 * 18 + lv1) * 4;
      const int b10 = (lc * 324 + lu1 * 18 + lv0) * 4;
      const int b11 = (lc * 324 + lu1 * 18 + lv1) * 4;
      const float gv = gw[4 + lc][k];
#pragma unroll
      for (int s = 0; s < 4; ++s) {
        float val = w00 * ls4[b00 + s] + w01 * ls4[b01 + s] +
                    w10 * ls4[b10 + s] + w11 * ls4[b11 + s];
        acc[k][s] += gv * val;
      }
    }
  }
  // ---- store Sf: layout [img][s][h][w] ----
#pragma unroll
  for (int k = 0; k < 4; ++k) {
    const int h = h0 + g2 * 4 + k;
    size_t base = (size_t)img * 4 * HW + (size_t)h * 192 + wpx;
#pragma unroll
    for (int s = 0; s < 4; ++s) sf[base + (size_t)s * HW] = acc[k][s];
  }
}

// ---------------- final 1x1 projection 128 -> 32 ----------------
__global__ __launch_bounds__(256) void k_proj(
    const float* __restrict__ sf, const float* __restrict__ pw,
    const float* __restrict__ pb, float* __restrict__ out)
{
  __shared__ float pws[4096];   // transposed: [ch][o]
  __shared__ float pbs[32];
  int tid = threadIdx.x;
#pragma unroll
  for (int i = 0; i < 16; ++i) {
    int idx = tid + i * 256;
    int o = idx >> 7, ch = idx & 127;
    pws[ch * 32 + o] = pw[idx];
  }
  if (tid < 32) pbs[tid] = pb[tid];
  __syncthreads();
  const int lane = tid & 63, og = tid >> 6;
  const int pxb = blockIdx.x * 512 + lane;     // block covers 512 contiguous px
  const int b = (blockIdx.x * 512) / HW;       // uniform (512 | HW)
  const int p0 = pxb - b * HW;
  float acc[8][8];
#pragma unroll
  for (int j = 0; j < 8; ++j)
#pragma unroll
    for (int oo = 0; oo < 8; ++oo) acc[j][oo] = 0.f;
  for (int ch = 0; ch < 128; ++ch) {
    const float* sp = sf + ((size_t)(b * 128 + ch)) * HW + p0;
    float4 pa = *(const float4*)(pws + ch * 32 + og * 8);
    float4 pbv = *(const float4*)(pws + ch * 32 + og * 8 + 4);
    float pv[8] = {pa.x, pa.y, pa.z, pa.w, pbv.x, pbv.y, pbv.z, pbv.w};
#pragma unroll
    for (int j = 0; j < 8; ++j) {
      float v = sp[j * 64];
#pragma unroll
      for (int oo = 0; oo < 8; ++oo) acc[j][oo] += pv[oo] * v;
    }
  }
#pragma unroll
  for (int oo = 0; oo < 8; ++oo) {
    float* op = out + (size_t)(b * 32 + og * 8 + oo) * HW + p0;
    float bias = pbs[og * 8 + oo];
#pragma unroll
    for (int j = 0; j < 8; ++j) op[j * 64] = acc[j][oo] + bias;
  }
}

extern "C" void kernel_launch(void* const* d_in, const int* in_sizes, int n_in,
                              void* d_out, int out_size, void* d_ws, size_t ws_size,
                              hipStream_t stream) {
  (void)in_sizes; (void)n_in; (void)out_size; (void)ws_size;
  const float* x    = (const float*)d_in[0];
  const float* gw1  = (const float*)d_in[1];
  const float* gb1  = (const float*)d_in[2];
  const float* gw2  = (const float*)d_in[3];
  const float* gb2  = (const float*)d_in[4];
  const float* s53A = (const float*)d_in[5];
  const float* s53D = (const float*)d_in[6];
  const float* s97A = (const float*)d_in[7];
  const float* s97D = (const float*)d_in[8];
  const float* hfp  = (const float*)d_in[9];
  const float* pw   = (const float*)d_in[10];
  const float* pb   = (const float*)d_in[11];
  float* out = (float*)d_out;
  float* ws = (float*)d_ws;

  float* gate = ws;                         // 884736 floats
  float* half = ws + 884736;                // 9437184 floats (2 cand x 4 sub x 128 x 96x96)
  float* sf   = ws + 884736 + 9437184;      // 18874368 floats (128 x 4 x 192x192)
  float* awdw = sf;                         // aliased scratch (dead before sf written)

  hipLaunchKernelGGL(k_gate, dim3(576), dim3(256), 0, stream, x, gw1, gb1, gw2, gb2, gate);
  // bior53 (steps 0..1), bior97 (steps 2..5)
  hipLaunchKernelGGL(k_wlift, dim3(192, 128), dim3(192), 0, stream,
                     x, awdw, awdw + 2359296, s53A, s53D, 0, 2);
  hipLaunchKernelGGL(k_wlift, dim3(192, 128), dim3(192), 0, stream,
                     x, awdw + 4718592, awdw + 4718592 + 2359296, s97A, s97D, 2, 4);
  hipLaunchKernelGGL(k_hlift, dim3(12, 128, 2), dim3(768), 0, stream,
                     awdw, half, s53A, s53D, hfp, 0, 2);
  hipLaunchKernelGGL(k_hlift, dim3(12, 128, 2), dim3(768), 0, stream,
                     awdw + 4718592, half + 4718592, s97A, s97D, hfp, 2, 4);
  hipLaunchKernelGGL(k3_fused, dim3(36, 128), dim3(256), 0, stream, x, gate, half, hfp, sf);
  hipLaunchKernelGGL(k_proj, dim3(288), dim3(256), 0, stream, sf, pw, pb, out);
}